// Round 5
// baseline (248.473 us; speedup 1.0000x reference)
//
#include <hip/hip_runtime.h>

typedef unsigned short u16;
typedef unsigned int u32;
typedef unsigned long long u64;
typedef _Float16 f16x8 __attribute__((ext_vector_type(8)));
typedef float f32x4 __attribute__((ext_vector_type(4)));

__device__ __forceinline__ u16 f2h(float f) {
  union { _Float16 h; u16 u; } c; c.h = (_Float16)f; return c.u;
}
__device__ __forceinline__ float h2f(u16 v) {
  union { u16 u; _Float16 h; } c; c.u = v; return (float)c.h;
}

__device__ __forceinline__ f32x4 mfma16(f16x8 a, f16x8 b, f32x4 c) {
  return __builtin_amdgcn_mfma_f32_16x16x32_f16(a, b, c, 0, 0, 0);
}

// 8 contiguous fp32 -> 8 fp16 (u16)
__device__ __forceinline__ void ld8f(const float* s, u16* o) {
  float4 a = *(const float4*)s;
  float4 b = *(const float4*)(s + 4);
  o[0] = f2h(a.x); o[1] = f2h(a.y); o[2] = f2h(a.z); o[3] = f2h(a.w);
  o[4] = f2h(b.x); o[5] = f2h(b.y); o[6] = f2h(b.z); o[7] = f2h(b.w);
}

// pack two float4-pairs (8 floats) to 8 fp16
__device__ __forceinline__ void cvt8(float4 a, float4 b, u16* o) {
  o[0] = f2h(a.x); o[1] = f2h(a.y); o[2] = f2h(a.z); o[3] = f2h(a.w);
  o[4] = f2h(b.x); o[5] = f2h(b.y); o[6] = f2h(b.z); o[7] = f2h(b.w);
}

// async global->LDS 16B direct load. LDS dest wave-uniform base; HW adds lane*16.
__device__ __forceinline__ void glds16(const u16* g, u16* l) {
  __builtin_amdgcn_global_load_lds(
      reinterpret_cast<const __attribute__((address_space(1))) u32*>(reinterpret_cast<u64>(g)),
      reinterpret_cast<__attribute__((address_space(3))) u32*>(reinterpret_cast<u64>(l)),
      16, 0, 0);
}

// ---------------------------------------------------------------------------
// Counted-vmcnt pipelined NT tile core: C[BM,BN] += A[BM,K]*B[BN,K]^T.
// fp16-in-u16, BOTH operands K-contiguous, glds-staged.
//   WM x WN wave grid (NT = WM*WN*64 threads), per wave TM x TN 16x16 tiles.
//   BM = WM*TM*16, BN = WN*TN*16.
//   DEPTH buffers, PF = DEPTH-2 deep prefetch: iter kt stages tile kt+PF,
//   waits s_waitcnt vmcnt(PF*VPI) -> PF tiles stay in flight across barrier.
//   Race-safe: stage index differs from any buffer still being read
//   (per-iter barrier rendezvous bounds wave skew to < 1 iter).
// LDS tile: linear [row][32 u16]; phys 16B-chunk c of row r holds logical
// k-chunk c ^ ((r>>1)&3) (same involution on stage source & fragment read
// -> ds_read_b128 2-way bank-aliased max = free).
// ---------------------------------------------------------------------------
template<int TM, int TN, int WM, int WN, int DEPTH>
__device__ __forceinline__ void gemm_core(const u16* __restrict__ A, int lda,
                                          const u16* __restrict__ B, int ldb,
                                          int ksteps, u16* sA, u16* sB, f32x4 acc[TM][TN]) {
  constexpr int NT = WM * WN * 64;
  constexpr int BM = WM * TM * 16, BN = WN * TN * 16;
  constexpr int TILEA = BM * 32, TILEB = BN * 32;   // u16 per buffer
  constexpr int APF = (BM * 4) / NT, BPF = (BN * 4) / NT;  // glds/thread
  constexpr int VPI = APF + BPF;                    // vmem issued per iter
  constexpr int PF = DEPTH - 2;                     // prefetch depth
  static_assert(PF == 1 || PF == 2, "");
  static_assert(APF >= 1 && BPF >= 1, "");

  const int t = threadIdx.x;
  const int lane = t & 63, wave = t >> 6;
  const int wm = wave / WN, wn = wave % WN;
  const int m16 = lane & 15, q4 = lane >> 4;

  // stage addressing: slot s -> row=s>>2, phys chunk c=s&3 holds logical
  // chunk c ^ ((row>>1)&3) (pre-swizzled global source, linear LDS dest).
  int aoff[APF], asl[APF];
#pragma unroll
  for (int p = 0; p < APF; ++p) {
    int s = p * NT + t, row = s >> 2;
    int kc = (s & 3) ^ ((row >> 1) & 3);
    aoff[p] = row * lda + kc * 8;
    asl[p] = (p * NT + (wave << 6)) * 8;  // wave-uniform LDS u16 base
  }
  int boff[BPF], bsl[BPF];
#pragma unroll
  for (int p = 0; p < BPF; ++p) {
    int s = p * NT + t, row = s >> 2;
    int kc = (s & 3) ^ ((row >> 1) & 3);
    boff[p] = row * ldb + kc * 8;
    bsl[p] = (p * NT + (wave << 6)) * 8;
  }

  // fragment read offsets (u16), loop-invariant
  int aro[TM], bro[TN];
#pragma unroll
  for (int i = 0; i < TM; ++i) {
    int row = wm * TM * 16 + i * 16 + m16;
    aro[i] = row * 32 + ((q4 ^ ((row >> 1) & 3)) << 3);
  }
#pragma unroll
  for (int j = 0; j < TN; ++j) {
    int row = wn * TN * 16 + j * 16 + m16;
    bro[j] = row * 32 + ((q4 ^ ((row >> 1) & 3)) << 3);
  }

  // prologue: stage tiles 0..PF-1 into buffers 0..PF-1 (ksteps >= 16 > PF)
#pragma unroll
  for (int j = 0; j < PF; ++j) {
    const u16* Aj = A + j * 32;
    u16* aS = sA + j * TILEA;
#pragma unroll
    for (int p = 0; p < APF; ++p) glds16(Aj + aoff[p], aS + asl[p]);
    const u16* Bj = B + j * 32;
    u16* bS = sB + j * TILEB;
#pragma unroll
    for (int p = 0; p < BPF; ++p) glds16(Bj + boff[p], bS + bsl[p]);
  }

  int cur = 0, stg = PF;  // read index, stage index = (cur+PF)%DEPTH
#pragma unroll 1
  for (int kt = 0; kt < ksteps; ++kt) {
    if (kt + PF < ksteps) {
      const u16* An = A + (size_t)(kt + PF) * 32;
      u16* aS = sA + stg * TILEA;
#pragma unroll
      for (int p = 0; p < APF; ++p) glds16(An + aoff[p], aS + asl[p]);
      const u16* Bn = B + (size_t)(kt + PF) * 32;
      u16* bS = sB + stg * TILEB;
#pragma unroll
      for (int p = 0; p < BPF; ++p) glds16(Bn + boff[p], bS + bsl[p]);
    }
    // tile kt (oldest) must land; up to PF future tiles stay in flight.
    if (PF == 2 && kt + 2 < ksteps)
      asm volatile("s_waitcnt vmcnt(%0)" :: "n"(2 * VPI) : "memory");
    else if (kt + 1 < ksteps)
      asm volatile("s_waitcnt vmcnt(%0)" :: "n"(VPI) : "memory");
    else
      asm volatile("s_waitcnt vmcnt(0)" ::: "memory");
    __builtin_amdgcn_s_barrier();
    __builtin_amdgcn_sched_barrier(0);  // nothing crosses the barrier

    const u16* aR = sA + cur * TILEA;
    const u16* bR = sB + cur * TILEB;
    f16x8 af[TM], bv[TN];
#pragma unroll
    for (int i = 0; i < TM; ++i) af[i] = *(const f16x8*)&aR[aro[i]];
#pragma unroll
    for (int j = 0; j < TN; ++j) bv[j] = *(const f16x8*)&bR[bro[j]];
#pragma unroll
    for (int i = 0; i < TM; ++i)
#pragma unroll
      for (int j = 0; j < TN; ++j)
        acc[i][j] = mfma16(af[i], bv[j], acc[i][j]);

    cur = (cur + 1 == DEPTH) ? 0 : cur + 1;
    stg = (stg + 1 == DEPTH) ? 0 : stg + 1;
  }
}

// Merged prep.
// blocks [0,512): x -> xh + xhT. One block per (b, nt) 64-n-column strip;
//   loops ot=0..7 (8 64x64 tiles) with double-buffered LDS and 1-tile-ahead
//   global prefetch: tile k+1's loads issue before tile k's barrier, so HBM
//   latency hides under the transpose+store work (fixes the latency-chain
//   bound seen at 2.5 TB/s).
// [512,1024): q -> qh + row sums; [1024,1280): vwT; [1280,1408): kwh; 1408: beta=0.
__global__ __launch_bounds__(256) void prep_all_kernel(const float* __restrict__ x,
                                                       u16* __restrict__ xh, u16* __restrict__ xhT,
                                                       const float* __restrict__ q, u16* __restrict__ qh,
                                                       float* __restrict__ qs,
                                                       const float* __restrict__ vw, u16* __restrict__ vwT,
                                                       const float* __restrict__ kw, u16* __restrict__ kwh,
                                                       float* __restrict__ beta) {
  __shared__ __align__(16) u16 T[2 * 64 * 72];
  int blk = blockIdx.x, t = threadIdx.x;
  if (blk < 512) {
    int nt = blk & 63, b = blk >> 6;
    int s = t & 31;        // o-pair index (o_local = 2s, 2s+1)
    int c = (t >> 5) * 8;  // n_local base
    const float* xbase = x + ((size_t)b * 512 + 2 * s) * 4096 + nt * 64 + c;
    int rr = t >> 2, og = t & 3;

    // preload tile 0
    float4 ca0 = *(const float4*)xbase;
    float4 ca1 = *(const float4*)(xbase + 4);
    float4 cb0 = *(const float4*)(xbase + 4096);
    float4 cb1 = *(const float4*)(xbase + 4100);

#pragma unroll 1
    for (int ot = 0; ot < 8; ++ot) {
      float4 na0, na1, nb0, nb1;
      if (ot < 7) {
        const float* np = xbase + (size_t)(ot + 1) * 64 * 4096;
        na0 = *(const float4*)np;
        na1 = *(const float4*)(np + 4);
        nb0 = *(const float4*)(np + 4096);
        nb1 = *(const float4*)(np + 4100);
      }
      u16 r0[8], r1[8];
      cvt8(ca0, ca1, r0);
      cvt8(cb0, cb1, r1);

      // xh pass-through (coalesced)
      u16* xq = xh + ((size_t)b * 512 + ot * 64 + 2 * s) * 4096 + nt * 64 + c;
      *(int4*)xq = *(int4*)r0;
      *(int4*)(xq + 4096) = *(int4*)r1;

      // LDS transpose write, buffer ot&1: T[n_local][o_local] packed u32
      u32* Tw = (u32*)(T + (ot & 1) * 4608);
#pragma unroll
      for (int e = 0; e < 8; ++e)
        Tw[(c + e) * 36 + s] = (u32)r0[e] | ((u32)r1[e] << 16);
      __syncthreads();

      const u16* Tr = T + (ot & 1) * 4608;
      int4 v0 = *(const int4*)&Tr[rr * 72 + og * 16];
      int4 v1 = *(const int4*)&Tr[rr * 72 + og * 16 + 8];
      u16* xo = xhT + ((size_t)b * 4096 + nt * 64 + rr) * 512 + ot * 64 + og * 16;
      *(int4*)xo = v0;
      *(int4*)(xo + 8) = v1;

      ca0 = na0; ca1 = na1; cb0 = nb0; cb1 = nb1;
    }
  } else if (blk < 1024) {
    int row = blk - 512;
    float s = 0.f;
#pragma unroll
    for (int p = 0; p < 2; ++p) {
      size_t i = (size_t)row * 4096 + p * 2048 + t * 8;
      u16 o[8];
      ld8f(q + i, o);
#pragma unroll
      for (int e = 0; e < 8; ++e) s += h2f(o[e]);
      *(int4*)&qh[i] = *(int4*)o;
    }
    for (int off = 32; off; off >>= 1) s += __shfl_xor(s, off);
    __shared__ float wsum[4];
    if ((t & 63) == 0) wsum[t >> 6] = s;
    __syncthreads();
    if (t == 0) qs[row] = wsum[0] + wsum[1] + wsum[2] + wsum[3];
  } else if (blk < 1280) {
    int bi = blk - 1024;
    u16* sT = T;  // reuse (needs 32*33)
    int bx = bi & 15, by = bi >> 4;
#pragma unroll
    for (int p = 0; p < 4; ++p) {
      int idx = p * 256 + t; int r = idx >> 5, c = idx & 31;
      sT[r * 33 + c] = f2h(vw[(size_t)(by * 32 + r) * 512 + bx * 32 + c]);
    }
    __syncthreads();
#pragma unroll
    for (int p = 0; p < 4; ++p) {
      int idx = p * 256 + t; int r = idx >> 5, c = idx & 31;
      vwT[(size_t)(bx * 32 + r) * 512 + by * 32 + c] = sT[c * 33 + r];
    }
  } else if (blk < 1408) {
    size_t i = ((size_t)(blk - 1280) * 256 + t) * 8;
    u16 o[8];
    ld8f(kw + i, o);
    *(int4*)&kwh[i] = *(int4*)o;
  } else {
    for (int i = t; i < 4096; i += 256) beta[i] = 0.f;
  }
}

// Sh[b][y][o] = sum_n q[y,n]*x[(b,o),n]; 128x128 tiles (halves L2/L3 operand
// streaming 512->256 MB, the measured wall), K=4096, 2-deep prefetch.
__global__ __launch_bounds__(256) void sgemm_kernel(const u16* __restrict__ qh, const u16* __restrict__ xh,
                                                    u16* __restrict__ Sh) {
  __shared__ __align__(16) u16 sA[4 * 128 * 32], sB[4 * 128 * 32];
  int rt = blockIdx.x, jt = blockIdx.y;
  f32x4 acc[4][4];
#pragma unroll
  for (int i = 0; i < 4; ++i)
#pragma unroll
    for (int j = 0; j < 4; ++j) acc[i][j] = (f32x4){0.f, 0.f, 0.f, 0.f};
  gemm_core<4, 4, 2, 2, 4>(qh + (size_t)jt * 128 * 4096, 4096,
                           xh + (size_t)rt * 128 * 4096, 4096, 128, sA, sB, acc);

  const int t = threadIdx.x, lane = t & 63, wave = t >> 6;
  const int wm = wave >> 1, wn = wave & 1, m16 = lane & 15, q4 = lane >> 4;
  int b = rt >> 2, o0 = (rt & 3) * 128;
  u16* Ob = Sh + (size_t)b * 262144;
#pragma unroll
  for (int i = 0; i < 4; ++i)
#pragma unroll
    for (int j = 0; j < 4; ++j)
#pragma unroll
      for (int r = 0; r < 4; ++r) {
        int y = jt * 128 + wm * 64 + i * 16 + q4 * 4 + r;
        int o = o0 + wn * 64 + j * 16 + m16;
        Ob[(size_t)y * 512 + o] = f2h(acc[i][j][r]);
      }
}

// E[b,x,y] = sum_o kw[x,o] * Sh[b][y][o]
__global__ __launch_bounds__(256) void egemm_kernel(const u16* __restrict__ kwh, const u16* __restrict__ Sh,
                                                    float* __restrict__ E) {
  __shared__ __align__(16) u16 sA[4 * 64 * 32], sB[4 * 64 * 32];
  int xt = blockIdx.x >> 3, yt = blockIdx.x & 7, b = blockIdx.y;
  f32x4 acc[2][2];
#pragma unroll
  for (int i = 0; i < 2; ++i)
#pragma unroll
    for (int j = 0; j < 2; ++j) acc[i][j] = (f32x4){0.f, 0.f, 0.f, 0.f};
  gemm_core<2, 2, 2, 2, 4>(kwh + (size_t)xt * 64 * 512, 512,
                           Sh + (size_t)b * 262144 + (size_t)yt * 64 * 512, 512, 16, sA, sB, acc);

  const int t = threadIdx.x, lane = t & 63, wave = t >> 6;
  const int wm = wave >> 1, wn = wave & 1, m16 = lane & 15, q4 = lane >> 4;
  float* O = E + ((size_t)b * 512 + xt * 64) * 512 + yt * 64;
#pragma unroll
  for (int i = 0; i < 2; ++i)
#pragma unroll
    for (int j = 0; j < 2; ++j)
#pragma unroll
      for (int r = 0; r < 4; ++r) {
        int row = wm * 32 + i * 16 + q4 * 4 + r;
        int col = wn * 32 + j * 16 + m16;
        O[(size_t)row * 512 + col] = acc[i][j][r];
      }
}

// softmax over y of (E[b,x,y]+kb[x]*qs[y]); writes attT[b][y][x] fp16; beta[b][y] += sum_x att*vb[x]
__global__ __launch_bounds__(256) void softmax_kernel(const float* __restrict__ E, const float* __restrict__ qs,
                                                      const float* __restrict__ kb, const float* __restrict__ vb,
                                                      u16* __restrict__ attT, float* __restrict__ beta) {
  __shared__ float sE[16 * 516];
  __shared__ float sM[16], sS[16];
  int i0 = blockIdx.x * 16, b = blockIdx.y, t = threadIdx.x;
  const float* Eb = E + ((size_t)b * 512 + i0) * 512;
  for (int ch = 0; ch < 32; ++ch) {
    int idx = ch * 256 + t;
    int row = idx >> 9, col = idx & 511;
    sE[row * 516 + col] = Eb[(size_t)row * 512 + col] + kb[i0 + row] * qs[col];
  }
  __syncthreads();
  {
    int row = t >> 4, sub = t & 15;
    float mx = -1e30f;
    for (int ii = 0; ii < 32; ++ii) mx = fmaxf(mx, sE[row * 516 + sub + ii * 16]);
    for (int off = 8; off; off >>= 1) mx = fmaxf(mx, __shfl_xor(mx, off));
    float sm = 0.f;
    for (int ii = 0; ii < 32; ++ii) sm += __expf(sE[row * 516 + sub + ii * 16] - mx);
    for (int off = 8; off; off >>= 1) sm += __shfl_xor(sm, off);
    if (sub == 0) { sM[row] = mx; sS[row] = 1.f / sm; }
  }
  __syncthreads();
  float vbr = vb[i0 + (t & 15)];
  u16* Ob = attT + (size_t)b * 262144;
  for (int ch = 0; ch < 32; ++ch) {
    int idx = ch * 256 + t;
    int r = idx & 15, j = idx >> 4;
    float a = __expf(sE[r * 516 + j] - sM[r]) * sS[r];
    Ob[(size_t)j * 512 + i0 + r] = f2h(a);
    float part = a * vbr;
    for (int off = 8; off; off >>= 1) part += __shfl_xor(part, off);
    if (r == 0) atomicAdd(&beta[b * 512 + j], part);
  }
}

// W[b][c][o] = sum_x attT[b][c][x] * vwT[o][x]
__global__ __launch_bounds__(256) void wgemm_kernel(const u16* __restrict__ attT, const u16* __restrict__ vwT,
                                                    u16* __restrict__ W) {
  __shared__ __align__(16) u16 sA[4 * 64 * 32], sB[4 * 64 * 32];
  int ct = blockIdx.x >> 3, ot = blockIdx.x & 7, b = blockIdx.y;
  f32x4 acc[2][2];
#pragma unroll
  for (int i = 0; i < 2; ++i)
#pragma unroll
    for (int j = 0; j < 2; ++j) acc[i][j] = (f32x4){0.f, 0.f, 0.f, 0.f};
  gemm_core<2, 2, 2, 2, 4>(attT + (size_t)b * 262144 + (size_t)ct * 64 * 512, 512,
                           vwT + (size_t)ot * 64 * 512, 512, 16, sA, sB, acc);

  const int t = threadIdx.x, lane = t & 63, wave = t >> 6;
  const int wm = wave >> 1, wn = wave & 1, m16 = lane & 15, q4 = lane >> 4;
  u16* O = W + (size_t)b * 262144 + (size_t)(ct * 64) * 512 + ot * 64;
#pragma unroll
  for (int i = 0; i < 2; ++i)
#pragma unroll
    for (int j = 0; j < 2; ++j)
#pragma unroll
      for (int r = 0; r < 4; ++r) {
        int row = wm * 32 + i * 16 + q4 * 4 + r;
        int col = wn * 32 + j * 16 + m16;
        O[(size_t)row * 512 + col] = f2h(acc[i][j][r]);
      }
}

// out[b,c,n] = gamma*(sum_o W[b,c,o]*xhT[b,n,o] + beta[b,c]) + x[b,c,n]  (fp32 out)
// 128x128 tile (r3 best), 2-deep prefetch for the L3-latency operand streams.
__global__ __launch_bounds__(256) void outgemm_kernel(const u16* __restrict__ W, const u16* __restrict__ xhT,
                                                      const float* __restrict__ x, const float* __restrict__ beta,
                                                      const float* __restrict__ gm, float* __restrict__ out) {
  __shared__ __align__(16) u16 sA[4 * 128 * 32], sB[4 * 128 * 32];
  int nt = blockIdx.x, ct = blockIdx.y, b = blockIdx.z;
  f32x4 acc[4][4];
#pragma unroll
  for (int i = 0; i < 4; ++i)
#pragma unroll
    for (int j = 0; j < 4; ++j) acc[i][j] = (f32x4){0.f, 0.f, 0.f, 0.f};
  gemm_core<4, 4, 2, 2, 4>(W + (size_t)b * 262144 + (size_t)ct * 128 * 512, 512,
                           xhT + (size_t)b * 2097152 + (size_t)nt * 128 * 512, 512, 16, sA, sB, acc);

  const int t = threadIdx.x, lane = t & 63, wave = t >> 6;
  const int wm = wave >> 1, wn = wave & 1, m16 = lane & 15, q4 = lane >> 4;
  float g = gm[0];
#pragma unroll
  for (int i = 0; i < 4; ++i)
#pragma unroll
    for (int j = 0; j < 4; ++j)
#pragma unroll
      for (int r = 0; r < 4; ++r) {
        int c = ct * 128 + wm * 64 + i * 16 + q4 * 4 + r;
        int n = nt * 128 + wn * 64 + j * 16 + m16;
        size_t idx = (size_t)b * 2097152 + (size_t)c * 4096 + n;
        out[idx] = g * (acc[i][j][r] + beta[b * 512 + c]) + x[idx];
      }
}

extern "C" void kernel_launch(void* const* d_in, const int* in_sizes, int n_in,
                              void* d_out, int out_size, void* d_ws, size_t ws_size,
                              hipStream_t stream) {
  const float* x  = (const float*)d_in[0];
  const float* pq = (const float*)d_in[1];
  const float* kw = (const float*)d_in[2];
  const float* kb = (const float*)d_in[3];
  const float* vw = (const float*)d_in[4];
  const float* vb = (const float*)d_in[5];
  const float* gm = (const float*)d_in[6];
  float* out = (float*)d_out;

  // workspace: 86 MB
  char* ws = (char*)d_ws;
  u16*   xh   = (u16*)(ws);                            // [0,32M)  fp16 x [b][o][n]
  u16*   qh   = (u16*)(ws + (32ull << 20));            // [32,36M)
  u16*   Sh   = (u16*)(ws + (36ull << 20));            // [36,40M) reused as W after egemm
  u16*   W    = (u16*)(ws + (36ull << 20));
  float* E    = (float*)(ws + (40ull << 20));          // [40,48M) fp32
  u16*   attT = (u16*)(ws + (48ull << 20));            // [48,52M)
  u16*   kwh  = (u16*)(ws + (52ull << 20));            // 512K
  u16*   vwT  = (u16*)(ws + (52ull << 20) + 524288);   // 512K
  char*  sm   = ws + (53ull << 20);                    // small region
  float* qs   = (float*)(sm);
  float* beta = (float*)(sm + 4096);                   // 16K
  u16*   xhT  = (u16*)(ws + (54ull << 20));            // [54,86M) fp16 x^T [b][n][o]

  prep_all_kernel<<<dim3(1409), 256, 0, stream>>>(x, xh, xhT, pq, qh, qs, vw, vwT, kw, kwh, beta);
  sgemm_kernel<<<dim3(32, 4), 256, 0, stream>>>(qh, xh, Sh);
  egemm_kernel<<<dim3(64, 8), 256, 0, stream>>>(kwh, Sh, E);
  softmax_kernel<<<dim3(32, 8), 256, 0, stream>>>(E, qs, kb, vb, attT, beta);
  wgemm_kernel<<<dim3(64, 8), 256, 0, stream>>>(attT, vwT, W);
  outgemm_kernel<<<dim3(32, 4, 8), 256, 0, stream>>>(W, xhT, x, beta, gm, out);
}

// Round 6
// 238.461 us; speedup vs baseline: 1.0420x; 1.0420x over previous
//
#include <hip/hip_runtime.h>

typedef unsigned short u16;
typedef unsigned int u32;
typedef unsigned long long u64;
typedef _Float16 f16x8 __attribute__((ext_vector_type(8)));
typedef float f32x4 __attribute__((ext_vector_type(4)));

__device__ __forceinline__ u16 f2h(float f) {
  union { _Float16 h; u16 u; } c; c.h = (_Float16)f; return c.u;
}
__device__ __forceinline__ float h2f(u16 v) {
  union { u16 u; _Float16 h; } c; c.u = v; return (float)c.h;
}

__device__ __forceinline__ f32x4 mfma16(f16x8 a, f16x8 b, f32x4 c) {
  return __builtin_amdgcn_mfma_f32_16x16x32_f16(a, b, c, 0, 0, 0);
}

// 8 contiguous fp32 -> 8 fp16 (u16)
__device__ __forceinline__ void ld8f(const float* s, u16* o) {
  float4 a = *(const float4*)s;
  float4 b = *(const float4*)(s + 4);
  o[0] = f2h(a.x); o[1] = f2h(a.y); o[2] = f2h(a.z); o[3] = f2h(a.w);
  o[4] = f2h(b.x); o[5] = f2h(b.y); o[6] = f2h(b.z); o[7] = f2h(b.w);
}

// pack two float4-pairs (8 floats) to 8 fp16
__device__ __forceinline__ void cvt8(float4 a, float4 b, u16* o) {
  o[0] = f2h(a.x); o[1] = f2h(a.y); o[2] = f2h(a.z); o[3] = f2h(a.w);
  o[4] = f2h(b.x); o[5] = f2h(b.y); o[6] = f2h(b.z); o[7] = f2h(b.w);
}

// async global->LDS 16B direct load. LDS dest wave-uniform base; HW adds lane*16.
__device__ __forceinline__ void glds16(const u16* g, u16* l) {
  __builtin_amdgcn_global_load_lds(
      reinterpret_cast<const __attribute__((address_space(1))) u32*>(reinterpret_cast<u64>(g)),
      reinterpret_cast<__attribute__((address_space(3))) u32*>(reinterpret_cast<u64>(l)),
      16, 0, 0);
}

// ---------------------------------------------------------------------------
// Counted-vmcnt pipelined NT tile core: C[BM,BN] += A[BM,K]*B[BN,K]^T.
// fp16-in-u16, BOTH operands K-contiguous, glds-staged.
//   WM x WN wave grid (NT = WM*WN*64 threads), per wave TM x TN 16x16 tiles.
//   DEPTH buffers, PF = DEPTH-2 deep prefetch, s_waitcnt vmcnt(PF*VPI):
//   PF tiles stay in flight across the barrier.
// LDS tile: linear [row][32 u16]; phys 16B-chunk c of row r holds logical
// k-chunk c ^ ((r>>1)&3) (same involution on stage source & fragment read
// -> ds_read_b128 2-way bank-aliased max = free).
// ---------------------------------------------------------------------------
template<int TM, int TN, int WM, int WN, int DEPTH>
__device__ __forceinline__ void gemm_core(const u16* __restrict__ A, int lda,
                                          const u16* __restrict__ B, int ldb,
                                          int ksteps, u16* sA, u16* sB, f32x4 acc[TM][TN]) {
  constexpr int NT = WM * WN * 64;
  constexpr int BM = WM * TM * 16, BN = WN * TN * 16;
  constexpr int TILEA = BM * 32, TILEB = BN * 32;   // u16 per buffer
  constexpr int APF = (BM * 4) / NT, BPF = (BN * 4) / NT;  // glds/thread
  constexpr int VPI = APF + BPF;                    // vmem issued per iter
  constexpr int PF = DEPTH - 2;                     // prefetch depth
  static_assert(PF == 1 || PF == 2, "");
  static_assert(APF >= 1 && BPF >= 1, "");

  const int t = threadIdx.x;
  const int lane = t & 63, wave = t >> 6;
  const int wm = wave / WN, wn = wave % WN;
  const int m16 = lane & 15, q4 = lane >> 4;

  int aoff[APF], asl[APF];
#pragma unroll
  for (int p = 0; p < APF; ++p) {
    int s = p * NT + t, row = s >> 2;
    int kc = (s & 3) ^ ((row >> 1) & 3);
    aoff[p] = row * lda + kc * 8;
    asl[p] = (p * NT + (wave << 6)) * 8;  // wave-uniform LDS u16 base
  }
  int boff[BPF], bsl[BPF];
#pragma unroll
  for (int p = 0; p < BPF; ++p) {
    int s = p * NT + t, row = s >> 2;
    int kc = (s & 3) ^ ((row >> 1) & 3);
    boff[p] = row * ldb + kc * 8;
    bsl[p] = (p * NT + (wave << 6)) * 8;
  }

  int aro[TM], bro[TN];
#pragma unroll
  for (int i = 0; i < TM; ++i) {
    int row = wm * TM * 16 + i * 16 + m16;
    aro[i] = row * 32 + ((q4 ^ ((row >> 1) & 3)) << 3);
  }
#pragma unroll
  for (int j = 0; j < TN; ++j) {
    int row = wn * TN * 16 + j * 16 + m16;
    bro[j] = row * 32 + ((q4 ^ ((row >> 1) & 3)) << 3);
  }

  // prologue: stage tiles 0..PF-1 into buffers 0..PF-1
#pragma unroll
  for (int j = 0; j < PF; ++j) {
    const u16* Aj = A + j * 32;
    u16* aS = sA + j * TILEA;
#pragma unroll
    for (int p = 0; p < APF; ++p) glds16(Aj + aoff[p], aS + asl[p]);
    const u16* Bj = B + j * 32;
    u16* bS = sB + j * TILEB;
#pragma unroll
    for (int p = 0; p < BPF; ++p) glds16(Bj + boff[p], bS + bsl[p]);
  }

  int cur = 0, stg = PF;
#pragma unroll 1
  for (int kt = 0; kt < ksteps; ++kt) {
    if (kt + PF < ksteps) {
      const u16* An = A + (size_t)(kt + PF) * 32;
      u16* aS = sA + stg * TILEA;
#pragma unroll
      for (int p = 0; p < APF; ++p) glds16(An + aoff[p], aS + asl[p]);
      const u16* Bn = B + (size_t)(kt + PF) * 32;
      u16* bS = sB + stg * TILEB;
#pragma unroll
      for (int p = 0; p < BPF; ++p) glds16(Bn + boff[p], bS + bsl[p]);
    }
    if (PF == 2 && kt + 2 < ksteps)
      asm volatile("s_waitcnt vmcnt(%0)" :: "n"(2 * VPI) : "memory");
    else if (kt + 1 < ksteps)
      asm volatile("s_waitcnt vmcnt(%0)" :: "n"(VPI) : "memory");
    else
      asm volatile("s_waitcnt vmcnt(0)" ::: "memory");
    __builtin_amdgcn_s_barrier();
    __builtin_amdgcn_sched_barrier(0);

    const u16* aR = sA + cur * TILEA;
    const u16* bR = sB + cur * TILEB;
    f16x8 af[TM], bv[TN];
#pragma unroll
    for (int i = 0; i < TM; ++i) af[i] = *(const f16x8*)&aR[aro[i]];
#pragma unroll
    for (int j = 0; j < TN; ++j) bv[j] = *(const f16x8*)&bR[bro[j]];
#pragma unroll
    for (int i = 0; i < TM; ++i)
#pragma unroll
      for (int j = 0; j < TN; ++j)
        acc[i][j] = mfma16(af[i], bv[j], acc[i][j]);

    cur = (cur + 1 == DEPTH) ? 0 : cur + 1;
    stg = (stg + 1 == DEPTH) ? 0 : stg + 1;
  }
}

// Merged prep (r5 version, unchanged — left top-5).
__global__ __launch_bounds__(256) void prep_all_kernel(const float* __restrict__ x,
                                                       u16* __restrict__ xh, u16* __restrict__ xhT,
                                                       const float* __restrict__ q, u16* __restrict__ qh,
                                                       float* __restrict__ qs,
                                                       const float* __restrict__ vw, u16* __restrict__ vwT,
                                                       const float* __restrict__ kw, u16* __restrict__ kwh,
                                                       float* __restrict__ beta) {
  __shared__ __align__(16) u16 T[2 * 64 * 72];
  int blk = blockIdx.x, t = threadIdx.x;
  if (blk < 512) {
    int nt = blk & 63, b = blk >> 6;
    int s = t & 31;
    int c = (t >> 5) * 8;
    const float* xbase = x + ((size_t)b * 512 + 2 * s) * 4096 + nt * 64 + c;
    int rr = t >> 2, og = t & 3;

    float4 ca0 = *(const float4*)xbase;
    float4 ca1 = *(const float4*)(xbase + 4);
    float4 cb0 = *(const float4*)(xbase + 4096);
    float4 cb1 = *(const float4*)(xbase + 4100);

#pragma unroll 1
    for (int ot = 0; ot < 8; ++ot) {
      float4 na0, na1, nb0, nb1;
      if (ot < 7) {
        const float* np = xbase + (size_t)(ot + 1) * 64 * 4096;
        na0 = *(const float4*)np;
        na1 = *(const float4*)(np + 4);
        nb0 = *(const float4*)(np + 4096);
        nb1 = *(const float4*)(np + 4100);
      }
      u16 r0[8], r1[8];
      cvt8(ca0, ca1, r0);
      cvt8(cb0, cb1, r1);

      u16* xq = xh + ((size_t)b * 512 + ot * 64 + 2 * s) * 4096 + nt * 64 + c;
      *(int4*)xq = *(int4*)r0;
      *(int4*)(xq + 4096) = *(int4*)r1;

      u32* Tw = (u32*)(T + (ot & 1) * 4608);
#pragma unroll
      for (int e = 0; e < 8; ++e)
        Tw[(c + e) * 36 + s] = (u32)r0[e] | ((u32)r1[e] << 16);
      __syncthreads();

      const u16* Tr = T + (ot & 1) * 4608;
      int4 v0 = *(const int4*)&Tr[rr * 72 + og * 16];
      int4 v1 = *(const int4*)&Tr[rr * 72 + og * 16 + 8];
      u16* xo = xhT + ((size_t)b * 4096 + nt * 64 + rr) * 512 + ot * 64 + og * 16;
      *(int4*)xo = v0;
      *(int4*)(xo + 8) = v1;

      ca0 = na0; ca1 = na1; cb0 = nb0; cb1 = nb1;
    }
  } else if (blk < 1024) {
    int row = blk - 512;
    float s = 0.f;
#pragma unroll
    for (int p = 0; p < 2; ++p) {
      size_t i = (size_t)row * 4096 + p * 2048 + t * 8;
      u16 o[8];
      ld8f(q + i, o);
#pragma unroll
      for (int e = 0; e < 8; ++e) s += h2f(o[e]);
      *(int4*)&qh[i] = *(int4*)o;
    }
    for (int off = 32; off; off >>= 1) s += __shfl_xor(s, off);
    __shared__ float wsum[4];
    if ((t & 63) == 0) wsum[t >> 6] = s;
    __syncthreads();
    if (t == 0) qs[row] = wsum[0] + wsum[1] + wsum[2] + wsum[3];
  } else if (blk < 1280) {
    int bi = blk - 1024;
    u16* sT = T;
    int bx = bi & 15, by = bi >> 4;
#pragma unroll
    for (int p = 0; p < 4; ++p) {
      int idx = p * 256 + t; int r = idx >> 5, c = idx & 31;
      sT[r * 33 + c] = f2h(vw[(size_t)(by * 32 + r) * 512 + bx * 32 + c]);
    }
    __syncthreads();
#pragma unroll
    for (int p = 0; p < 4; ++p) {
      int idx = p * 256 + t; int r = idx >> 5, c = idx & 31;
      vwT[(size_t)(bx * 32 + r) * 512 + by * 32 + c] = sT[c * 33 + r];
    }
  } else if (blk < 1408) {
    size_t i = ((size_t)(blk - 1280) * 256 + t) * 8;
    u16 o[8];
    ld8f(kw + i, o);
    *(int4*)&kwh[i] = *(int4*)o;
  } else {
    for (int i = t; i < 4096; i += 256) beta[i] = 0.f;
  }
}

// sgemm split-K: Sp[ks][b][y][o] = sum_{n in half ks} q[y,n]*x[(b,o),n].
// 128x128 tiles, split-2 over K -> 256 blocks (all CUs), Kchunk=2048,
// same 256 MB L2/L3 stream as unsplit 128^2 (traffic invariant under split).
__global__ __launch_bounds__(256) void sgemm_kernel(const u16* __restrict__ qh, const u16* __restrict__ xh,
                                                    float* __restrict__ Sp0, float* __restrict__ Sp1) {
  __shared__ __align__(16) u16 sA[4 * 128 * 32], sB[4 * 128 * 32];
  int rt = blockIdx.x, jt = blockIdx.y, ks = blockIdx.z;
  int b = rt >> 2, o0 = (rt & 3) * 128;
  f32x4 acc[4][4];
#pragma unroll
  for (int i = 0; i < 4; ++i)
#pragma unroll
    for (int j = 0; j < 4; ++j) acc[i][j] = (f32x4){0.f, 0.f, 0.f, 0.f};
  gemm_core<4, 4, 2, 2, 4>(qh + (size_t)jt * 128 * 4096 + (size_t)ks * 2048, 4096,
                           xh + ((size_t)b * 512 + o0) * 4096 + (size_t)ks * 2048, 4096,
                           64, sA, sB, acc);

  const int t = threadIdx.x, lane = t & 63, wave = t >> 6;
  const int wm = wave >> 1, wn = wave & 1, m16 = lane & 15, q4 = lane >> 4;
  float* Sp = ks ? Sp1 : Sp0;
  float* Ob = Sp + (size_t)b * 262144;
#pragma unroll
  for (int i = 0; i < 4; ++i)
#pragma unroll
    for (int j = 0; j < 4; ++j)
#pragma unroll
      for (int r = 0; r < 4; ++r) {
        int y = jt * 128 + wm * 64 + i * 16 + q4 * 4 + r;
        int o = o0 + wn * 64 + j * 16 + m16;
        Ob[(size_t)y * 512 + o] = acc[i][j][r];
      }
}

// Sh = f2h(Sp0 + Sp1)
__global__ __launch_bounds__(256) void sreduce_kernel(const float* __restrict__ Sp0,
                                                      const float* __restrict__ Sp1,
                                                      u16* __restrict__ Sh) {
  size_t i = ((size_t)blockIdx.x * 256 + threadIdx.x) * 8;
  float4 a0 = *(const float4*)(Sp0 + i);
  float4 a1 = *(const float4*)(Sp0 + i + 4);
  float4 b0 = *(const float4*)(Sp1 + i);
  float4 b1 = *(const float4*)(Sp1 + i + 4);
  a0.x += b0.x; a0.y += b0.y; a0.z += b0.z; a0.w += b0.w;
  a1.x += b1.x; a1.y += b1.y; a1.z += b1.z; a1.w += b1.w;
  u16 o[8];
  cvt8(a0, a1, o);
  *(int4*)&Sh[i] = *(int4*)o;
}

// E[b,x,y] = sum_o kw[x,o] * Sh[b][y][o]
__global__ __launch_bounds__(256) void egemm_kernel(const u16* __restrict__ kwh, const u16* __restrict__ Sh,
                                                    float* __restrict__ E) {
  __shared__ __align__(16) u16 sA[4 * 64 * 32], sB[4 * 64 * 32];
  int xt = blockIdx.x >> 3, yt = blockIdx.x & 7, b = blockIdx.y;
  f32x4 acc[2][2];
#pragma unroll
  for (int i = 0; i < 2; ++i)
#pragma unroll
    for (int j = 0; j < 2; ++j) acc[i][j] = (f32x4){0.f, 0.f, 0.f, 0.f};
  gemm_core<2, 2, 2, 2, 4>(kwh + (size_t)xt * 64 * 512, 512,
                           Sh + (size_t)b * 262144 + (size_t)yt * 64 * 512, 512, 16, sA, sB, acc);

  const int t = threadIdx.x, lane = t & 63, wave = t >> 6;
  const int wm = wave >> 1, wn = wave & 1, m16 = lane & 15, q4 = lane >> 4;
  float* O = E + ((size_t)b * 512 + xt * 64) * 512 + yt * 64;
#pragma unroll
  for (int i = 0; i < 2; ++i)
#pragma unroll
    for (int j = 0; j < 2; ++j)
#pragma unroll
      for (int r = 0; r < 4; ++r) {
        int row = wm * 32 + i * 16 + q4 * 4 + r;
        int col = wn * 32 + j * 16 + m16;
        O[(size_t)row * 512 + col] = acc[i][j][r];
      }
}

// softmax over y of (E[b,x,y]+kb[x]*qs[y]); writes attT[b][y][x] fp16; beta[b][y] += sum_x att*vb[x]
__global__ __launch_bounds__(256) void softmax_kernel(const float* __restrict__ E, const float* __restrict__ qs,
                                                      const float* __restrict__ kb, const float* __restrict__ vb,
                                                      u16* __restrict__ attT, float* __restrict__ beta) {
  __shared__ float sE[16 * 516];
  __shared__ float sM[16], sS[16];
  int i0 = blockIdx.x * 16, b = blockIdx.y, t = threadIdx.x;
  const float* Eb = E + ((size_t)b * 512 + i0) * 512;
  for (int ch = 0; ch < 32; ++ch) {
    int idx = ch * 256 + t;
    int row = idx >> 9, col = idx & 511;
    sE[row * 516 + col] = Eb[(size_t)row * 512 + col] + kb[i0 + row] * qs[col];
  }
  __syncthreads();
  {
    int row = t >> 4, sub = t & 15;
    float mx = -1e30f;
    for (int ii = 0; ii < 32; ++ii) mx = fmaxf(mx, sE[row * 516 + sub + ii * 16]);
    for (int off = 8; off; off >>= 1) mx = fmaxf(mx, __shfl_xor(mx, off));
    float sm = 0.f;
    for (int ii = 0; ii < 32; ++ii) sm += __expf(sE[row * 516 + sub + ii * 16] - mx);
    for (int off = 8; off; off >>= 1) sm += __shfl_xor(sm, off);
    if (sub == 0) { sM[row] = mx; sS[row] = 1.f / sm; }
  }
  __syncthreads();
  float vbr = vb[i0 + (t & 15)];
  u16* Ob = attT + (size_t)b * 262144;
  for (int ch = 0; ch < 32; ++ch) {
    int idx = ch * 256 + t;
    int r = idx & 15, j = idx >> 4;
    float a = __expf(sE[r * 516 + j] - sM[r]) * sS[r];
    Ob[(size_t)j * 512 + i0 + r] = f2h(a);
    float part = a * vbr;
    for (int off = 8; off; off >>= 1) part += __shfl_xor(part, off);
    if (r == 0) atomicAdd(&beta[b * 512 + j], part);
  }
}

// W[b][c][o] = sum_x attT[b][c][x] * vwT[o][x]
__global__ __launch_bounds__(256) void wgemm_kernel(const u16* __restrict__ attT, const u16* __restrict__ vwT,
                                                    u16* __restrict__ W) {
  __shared__ __align__(16) u16 sA[4 * 64 * 32], sB[4 * 64 * 32];
  int ct = blockIdx.x >> 3, ot = blockIdx.x & 7, b = blockIdx.y;
  f32x4 acc[2][2];
#pragma unroll
  for (int i = 0; i < 2; ++i)
#pragma unroll
    for (int j = 0; j < 2; ++j) acc[i][j] = (f32x4){0.f, 0.f, 0.f, 0.f};
  gemm_core<2, 2, 2, 2, 4>(attT + (size_t)b * 262144 + (size_t)ct * 64 * 512, 512,
                           vwT + (size_t)ot * 64 * 512, 512, 16, sA, sB, acc);

  const int t = threadIdx.x, lane = t & 63, wave = t >> 6;
  const int wm = wave >> 1, wn = wave & 1, m16 = lane & 15, q4 = lane >> 4;
  u16* O = W + (size_t)b * 262144 + (size_t)(ct * 64) * 512 + ot * 64;
#pragma unroll
  for (int i = 0; i < 2; ++i)
#pragma unroll
    for (int j = 0; j < 2; ++j)
#pragma unroll
      for (int r = 0; r < 4; ++r) {
        int row = wm * 32 + i * 16 + q4 * 4 + r;
        int col = wn * 32 + j * 16 + m16;
        O[(size_t)row * 512 + col] = f2h(acc[i][j][r]);
      }
}

// out[b,c,n] = gamma*(sum_o W[b,c,o]*xhT[b,n,o] + beta[b,c]) + x[b,c,n]  (fp32 out)
__global__ __launch_bounds__(256) void outgemm_kernel(const u16* __restrict__ W, const u16* __restrict__ xhT,
                                                      const float* __restrict__ x, const float* __restrict__ beta,
                                                      const float* __restrict__ gm, float* __restrict__ out) {
  __shared__ __align__(16) u16 sA[4 * 128 * 32], sB[4 * 128 * 32];
  int nt = blockIdx.x, ct = blockIdx.y, b = blockIdx.z;
  f32x4 acc[4][4];
#pragma unroll
  for (int i = 0; i < 4; ++i)
#pragma unroll
    for (int j = 0; j < 4; ++j) acc[i][j] = (f32x4){0.f, 0.f, 0.f, 0.f};
  gemm_core<4, 4, 2, 2, 4>(W + (size_t)b * 262144 + (size_t)ct * 128 * 512, 512,
                           xhT + (size_t)b * 2097152 + (size_t)nt * 128 * 512, 512, 16, sA, sB, acc);

  const int t = threadIdx.x, lane = t & 63, wave = t >> 6;
  const int wm = wave >> 1, wn = wave & 1, m16 = lane & 15, q4 = lane >> 4;
  float g = gm[0];
#pragma unroll
  for (int i = 0; i < 4; ++i)
#pragma unroll
    for (int j = 0; j < 4; ++j)
#pragma unroll
      for (int r = 0; r < 4; ++r) {
        int c = ct * 128 + wm * 64 + i * 16 + q4 * 4 + r;
        int n = nt * 128 + wn * 64 + j * 16 + m16;
        size_t idx = (size_t)b * 2097152 + (size_t)c * 4096 + n;
        out[idx] = g * (acc[i][j][r] + beta[b * 512 + c]) + x[idx];
      }
}

extern "C" void kernel_launch(void* const* d_in, const int* in_sizes, int n_in,
                              void* d_out, int out_size, void* d_ws, size_t ws_size,
                              hipStream_t stream) {
  const float* x  = (const float*)d_in[0];
  const float* pq = (const float*)d_in[1];
  const float* kw = (const float*)d_in[2];
  const float* kb = (const float*)d_in[3];
  const float* vw = (const float*)d_in[4];
  const float* vb = (const float*)d_in[5];
  const float* gm = (const float*)d_in[6];
  float* out = (float*)d_out;

  // workspace: 94 MB
  char* ws = (char*)d_ws;
  u16*   xh   = (u16*)(ws);                            // [0,32M)  fp16 x [b][o][n]
  u16*   qh   = (u16*)(ws + (32ull << 20));            // [32,36M)
  u16*   Sh   = (u16*)(ws + (36ull << 20));            // [36,40M) reused as W after egemm
  u16*   W    = (u16*)(ws + (36ull << 20));
  float* E    = (float*)(ws + (40ull << 20));          // [40,48M) fp32; Sp0 during sgemm
  float* Sp0  = (float*)(ws + (40ull << 20));
  u16*   attT = (u16*)(ws + (48ull << 20));            // [48,52M)
  u16*   kwh  = (u16*)(ws + (52ull << 20));            // 512K
  u16*   vwT  = (u16*)(ws + (52ull << 20) + 524288);   // 512K
  char*  sm   = ws + (53ull << 20);                    // small region
  float* qs   = (float*)(sm);
  float* beta = (float*)(sm + 4096);                   // 16K
  u16*   xhT  = (u16*)(ws + (54ull << 20));            // [54,86M) fp16 x^T [b][n][o]
  float* Sp1  = (float*)(ws + (86ull << 20));          // [86,94M) split-K partial 1

  prep_all_kernel<<<dim3(1409), 256, 0, stream>>>(x, xh, xhT, pq, qh, qs, vw, vwT, kw, kwh, beta);
  sgemm_kernel<<<dim3(32, 4, 2), 256, 0, stream>>>(qh, xh, Sp0, Sp1);
  sreduce_kernel<<<dim3(1024), 256, 0, stream>>>(Sp0, Sp1, Sh);
  egemm_kernel<<<dim3(64, 8), 256, 0, stream>>>(kwh, Sh, E);
  softmax_kernel<<<dim3(32, 8), 256, 0, stream>>>(E, qs, kb, vb, attT, beta);
  wgemm_kernel<<<dim3(64, 8), 256, 0, stream>>>(attT, vwT, W);
  outgemm_kernel<<<dim3(32, 4, 8), 256, 0, stream>>>(W, xhT, x, beta, gm, out);
}